// Round 1
// baseline (39.297 us; speedup 1.0000x reference)
//
#include <hip/hip_runtime.h>

// X = prod_{i=0}^{n-1} (I + A_i/n), left-to-right, A: [N,2,2] f32 row-major.
// Associative -> chunked serial products + ordered tree combines, fp64 accum.

struct M2 { double a, b, c, d; };  // [[a,b],[c,d]]

__device__ __forceinline__ M2 m2mul(const M2& X, const M2& Y) {
    M2 r;
    r.a = fma(X.a, Y.a, X.b * Y.c);
    r.b = fma(X.a, Y.b, X.b * Y.d);
    r.c = fma(X.c, Y.a, X.d * Y.c);
    r.d = fma(X.c, Y.b, X.d * Y.d);
    return r;
}

// Ordered wave tree combine: after step k, lane l holds product of chunks
// [l, l+2^(k+1)) (valid for all l with l+2^(k+1) <= 64). Lane 0 ends with all 64.
__device__ __forceinline__ M2 wave_combine(M2 P) {
    #pragma unroll
    for (int off = 1; off < 64; off <<= 1) {
        M2 Q;
        Q.a = __shfl_down(P.a, off);
        Q.b = __shfl_down(P.b, off);
        Q.c = __shfl_down(P.c, off);
        Q.d = __shfl_down(P.d, off);
        P = m2mul(P, Q);  // lower lane (earlier indices) on the left
    }
    return P;
}

#define P1_BLOCKS 512
#define P1_TPB 256
#define T_TOTAL (P1_BLOCKS * P1_TPB)
#define N_WAVES (T_TOTAL / 64)

__global__ void __launch_bounds__(P1_TPB) prodchain_phase1(
    const float4* __restrict__ A, int n, int chunk, double* __restrict__ part)
{
    const int t = blockIdx.x * P1_TPB + threadIdx.x;
    long start = (long)t * chunk;
    long end = start + chunk;
    if (end > n) end = n;
    const double inv_n = 1.0 / (double)n;

    M2 P = {1.0, 0.0, 0.0, 1.0};
    for (long i = start; i < end; ++i) {
        float4 v = A[i];
        M2 M;
        M.a = fma((double)v.x, inv_n, 1.0);
        M.b = (double)v.y * inv_n;
        M.c = (double)v.z * inv_n;
        M.d = fma((double)v.w, inv_n, 1.0);
        P = m2mul(P, M);
    }

    P = wave_combine(P);

    if ((threadIdx.x & 63) == 0) {
        int w = t >> 6;
        part[4 * w + 0] = P.a;
        part[4 * w + 1] = P.b;
        part[4 * w + 2] = P.c;
        part[4 * w + 3] = P.d;
    }
}

__global__ void prodchain_phase2(const double* __restrict__ part, int nw,
                                 float* __restrict__ out)
{
    const int l = threadIdx.x;      // single wave of 64
    const int per = nw >> 6;        // partials per lane
    M2 P = {1.0, 0.0, 0.0, 1.0};
    const int base = l * per;
    for (int i = base; i < base + per; ++i) {
        M2 Q = { part[4 * i + 0], part[4 * i + 1],
                 part[4 * i + 2], part[4 * i + 3] };
        P = m2mul(P, Q);
    }

    P = wave_combine(P);

    if (l == 0) {
        out[0] = (float)P.a;
        out[1] = (float)P.b;
        out[2] = (float)P.c;
        out[3] = (float)P.d;
    }
}

extern "C" void kernel_launch(void* const* d_in, const int* in_sizes, int n_in,
                              void* d_out, int out_size, void* d_ws, size_t ws_size,
                              hipStream_t stream) {
    const float4* A = (const float4*)d_in[0];
    const int n = in_sizes[0] / 4;          // number of 2x2 matrices
    double* part = (double*)d_ws;           // N_WAVES * 4 doubles = 64 KB
    const int chunk = (n + T_TOTAL - 1) / T_TOTAL;

    prodchain_phase1<<<P1_BLOCKS, P1_TPB, 0, stream>>>(A, n, chunk, part);
    prodchain_phase2<<<1, 64, 0, stream>>>(part, N_WAVES, (float*)d_out);
}